// Round 8
// baseline (297.079 us; speedup 1.0000x reference)
//
#include <hip/hip_runtime.h>

// ---------------------------------------------------------------------------
// LabelSimilarity: match[b,l] = max(-1, max_{s,v} cos(embed[s,b,:], label[l,v,:]))
// S=256 B=128 D=768 ; L=200 V=8 ; out [128,200] fp32
//
// R8: staging-volume attack. R3-R7 pinned at 150-166 us with all pipes <30%:
// the binding resource is global_load_lds DMA throughput (~42 B/cyc/CU per
// m97), and R6 staged 1.28 GB total. New tile: 256 M-rows (2 s per block,
// 512 thr / 8 waves) x 128 N -> 24 KB staged per 32-MFMA-per-wave iter
// (was 16 KB per 16) => total DMA 0.92 GB. In-block s-pair max halves
// scratch; one fused reduce kernel (3 launches total).
// ---------------------------------------------------------------------------

typedef __bf16 bf16x8 __attribute__((ext_vector_type(8)));
typedef float  f32x4  __attribute__((ext_vector_type(4)));

#define GLD16(gp, lp) __builtin_amdgcn_global_load_lds(                        \
    (__attribute__((address_space(1))) void*)(gp),                             \
    (__attribute__((address_space(3))) void*)(lp), 16, 0, 0)

__device__ __forceinline__ unsigned short f32_to_bf16_rne(float x) {
  unsigned u = __float_as_uint(x);
  u += 0x7fffu + ((u >> 16) & 1u);
  return (unsigned short)(u >> 16);
}

// One wave per row, both tensors in one launch:
// rows [0,32768) -> embed->Ap ; rows [32768, 32768+1664) -> label->Bp
// (label rows >= 1600 are zero pad).
__global__ void __launch_bounds__(256) normalize_all(
    const float* __restrict__ embed, const float* __restrict__ label,
    unsigned short* __restrict__ Ap, unsigned short* __restrict__ Bp) {
  int row  = blockIdx.x * 4 + (threadIdx.x >> 6);
  int lane = threadIdx.x & 63;
  const float* src;
  unsigned short* dstp;
  if (row < 32768) {
    src  = embed + (size_t)row * 768;
    dstp = Ap + (size_t)row * 768;
  } else {
    int lr = row - 32768;
    if (lr >= 1664) return;
    dstp = Bp + (size_t)lr * 768;
    if (lr >= 1600) {
      ushort4 z; z.x = z.y = z.z = z.w = 0;
      ushort4* drow = (ushort4*)dstp;
#pragma unroll
      for (int t = 0; t < 3; ++t) drow[lane + 64 * t] = z;
      return;
    }
    src = label + (size_t)lr * 768;
  }
  const float4* srow = (const float4*)src;
  ushort4* drow = (ushort4*)dstp;
  float4 v[3];
  float ss = 0.f;
#pragma unroll
  for (int t = 0; t < 3; ++t) {
    v[t] = srow[lane + 64 * t];
    ss += v[t].x * v[t].x + v[t].y * v[t].y + v[t].z * v[t].z + v[t].w * v[t].w;
  }
#pragma unroll
  for (int off = 1; off < 64; off <<= 1) ss += __shfl_xor(ss, off);
  float rinv = rsqrtf(fmaxf(ss, 1e-12f));
#pragma unroll
  for (int t = 0; t < 3; ++t) {
    ushort4 h;
    h.x = f32_to_bf16_rne(v[t].x * rinv);
    h.y = f32_to_bf16_rne(v[t].y * rinv);
    h.z = f32_to_bf16_rne(v[t].z * rinv);
    h.w = f32_to_bf16_rne(v[t].w * rinv);
    drow[lane + 64 * t] = h;
  }
}

// GEMM + per-block max tile. 512 threads = 8 waves in a 4(M)x2(N) grid of
// 64x64 wave tiles; block tile = 256 M-rows (s-pair 2*sg, 2*sg+1) x 128 N.
// Grid 1664, XCD-clustered. Writes scratch[(bx*128+sg)*2048 + b*16 + ll].
__global__ void __launch_bounds__(512, 4) gemm_store_kernel(
    const unsigned short* __restrict__ Ap,   // [32768][768] bf16 (normalized)
    const unsigned short* __restrict__ Bp,   // [1664][768]  bf16 (normalized)
    float* __restrict__ scratch) {
  __shared__ char smem[24576];   // A tile [256r][32k] @0, B tile [128r][32k] @16K

  const int t    = threadIdx.x;        // 0..511
  const int lane = t & 63;
  const int w    = t >> 6;             // wave 0..7

  // XCD-aware decode: blk -> (bx, sg); the 13 A-tile sharers co-locate.
  const int blk = blockIdx.x;          // 0..1663
  const int xcd = blk & 7;
  const int idx = blk >> 3;            // 0..207
  const int bx  = idx % 13;
  const int sg  = xcd * 16 + idx / 13; // 0..127  (s-pair {2sg, 2sg+1})
  const int n0  = bx * 128;

  // staging: slot (row=t>>2, cs=t&3) holds global chunk cg = cs^((row>>1)&3)
  // (swizzle stays inside the row's 64B line -> coalescing preserved).
  const int row = t >> 2;              // 0..127
  const int cg  = (t & 3) ^ ((t >> 3) & 3);
  const char* gA = (const char*)(Ap + (size_t)(sg * 256) * 768);
  const char* gB = (const char*)(Bp + (size_t)n0 * 768);
  const char* ga0 = gA + row * 1536 + cg * 16;           // A rows 0..127
  const char* ga1 = ga0 + 128 * 1536;                    // A rows 128..255
  const char* gb  = gB + row * 1536 + cg * 16;           // B rows 0..127
  char* const lA0 = smem + w * 1024;                     // t*16 in [0,8K)
  char* const lA1 = smem + 8192 + w * 1024;              // [8K,16K)
  char* const lB  = smem + 16384 + w * 1024;             // [16K,24K)

  // wave tile: 4x2 waves, each 64x64 = 4x4 MFMA tiles of 16x16
  const int wm  = (w >> 1) * 64;       // 0,64,128,192 (M)
  const int wn  = (w & 1) * 64;        // 0,64 (N)
  const int r16 = lane & 15;
  const int swz  = (((lane >> 4) ^ ((r16 >> 1) & 3)) * 16);   // bytes
  const int aoffB = (wm + r16) * 64 + swz;          // A region, row stride 64B
  const int boffB = 16384 + (wn + r16) * 64 + swz;  // B region

  f32x4 acc[4][4];
#pragma unroll
  for (int i = 0; i < 4; ++i)
#pragma unroll
    for (int j = 0; j < 4; ++j)
      acc[i][j] = (f32x4){0.f, 0.f, 0.f, 0.f};

  for (int kk = 0; kk < 24; ++kk) {    // K = 768 = 24 * 32
    GLD16(ga0, lA0); GLD16(ga1, lA1); GLD16(gb, lB);
    ga0 += 64; ga1 += 64; gb += 64;
    __syncthreads();                   // drains vmcnt -> tiles ready
    bf16x8 af[4], bfr[4];
#pragma unroll
    for (int i = 0; i < 4; ++i)
      af[i] = *(const bf16x8*)(smem + aoffB + i * 1024);
#pragma unroll
    for (int j = 0; j < 4; ++j)
      bfr[j] = *(const bf16x8*)(smem + boffB + j * 1024);
#pragma unroll
    for (int i = 0; i < 4; ++i)
#pragma unroll
      for (int j = 0; j < 4; ++j)
        acc[i][j] = __builtin_amdgcn_mfma_f32_16x16x32_bf16(
            af[i], bfr[j], acc[i][j], 0, 0, 0);
    __syncthreads();                   // protect LDS before next stage
  }

  // epilogue: acc is cos. C/D: col=lane&15, row=(lane>>4)*4+r.
  // max over v (col groups of 8) via shuffle; compact via LDS [2][128][17]
  // (one plane per s-half), fold the pair, coalesced float4 stores.
  float* red = (float*)smem;           // [2][128][17] = 17408 B
  const int rowg  = lane >> 4;
  const int lbit  = (lane >> 3) & 1;
  const bool writer = (lane & 7) == 0;
#pragma unroll
  for (int i = 0; i < 4; ++i) {
#pragma unroll
    for (int j = 0; j < 4; ++j) {
#pragma unroll
      for (int r = 0; r < 4; ++r) {
        float vv = acc[i][j][r];
        vv = fmaxf(vv, __shfl_xor(vv, 1));
        vv = fmaxf(vv, __shfl_xor(vv, 2));
        vv = fmaxf(vv, __shfl_xor(vv, 4));
        if (writer) {
          int m  = wm + i * 16 + rowg * 4 + r;   // 0..255
          int sh = m >> 7;                       // s-half
          int b  = m & 127;
          int ll = (wn >> 3) + j * 2 + lbit;     // 0..15
          red[(sh * 128 + b) * 17 + ll] = vv;
        }
      }
    }
  }
  __syncthreads();
  if (t < 256) {
    const int b  = t >> 1;
    const int l8 = (t & 1) * 8;
    const float* r0 = red + (b * 17 + l8);
    const float* r1 = red + ((128 + b) * 17 + l8);
    float4 p0, p1;
    p0.x = fmaxf(r0[0], r1[0]); p0.y = fmaxf(r0[1], r1[1]);
    p0.z = fmaxf(r0[2], r1[2]); p0.w = fmaxf(r0[3], r1[3]);
    p1.x = fmaxf(r0[4], r1[4]); p1.y = fmaxf(r0[5], r1[5]);
    p1.z = fmaxf(r0[6], r1[6]); p1.w = fmaxf(r0[7], r1[7]);
    float4* gg = (float4*)(scratch + ((size_t)(bx * 128 + sg)) * 2048 + t * 8);
    gg[0] = p0; gg[1] = p1;
  }
}

// fused reduce: out[b][l] = max(-1, max over 128 sg-tiles)
__global__ void __launch_bounds__(256) reduce_kernel(
    const float* __restrict__ scratch, float* __restrict__ out) {
  int idx = blockIdx.x * 256 + threadIdx.x;   // 0 .. 26623
  if (idx >= 13 * 2048) return;
  int bx = idx >> 11;
  int e  = idx & 2047;
  int b  = e >> 4;
  int ll = e & 15;
  int l  = bx * 16 + ll;
  if (l >= 200) return;
  const float* p = scratch + (size_t)(bx * 128) * 2048 + e;
  float m = -1.0f;
#pragma unroll 4
  for (int sg = 0; sg < 128; ++sg) m = fmaxf(m, p[(size_t)sg * 2048]);
  out[b * 200 + l] = m;
}

// Brute-force fp32 fallback (only if ws_size is too small): one block per (b,l).
__global__ void __launch_bounds__(256) fallback_kernel(
    const float* __restrict__ embed, const float* __restrict__ label,
    float* __restrict__ out) {
  int b = blockIdx.x, l = blockIdx.y, t = threadIdx.x;
  float m = -1.0f;
  for (int p = t; p < 2048; p += 256) {
    int s = p >> 3, v = p & 7;
    const float* e = embed + (size_t)(s * 128 + b) * 768;
    const float* q = label + (size_t)(l * 8 + v) * 768;
    float dot = 0.f, ne = 0.f, nl = 0.f;
    for (int d = 0; d < 768; ++d) {
      float x = e[d], y = q[d];
      dot += x * y; ne += x * x; nl += y * y;
    }
    m = fmaxf(m, dot / fmaxf(sqrtf(ne) * sqrtf(nl), 1e-8f));
  }
  for (int off = 1; off < 64; off <<= 1) m = fmaxf(m, __shfl_xor(m, off));
  __shared__ float wmax[4];
  if ((t & 63) == 0) wmax[t >> 6] = m;
  __syncthreads();
  if (t == 0)
    out[b * 200 + l] = fmaxf(fmaxf(wmax[0], wmax[1]), fmaxf(wmax[2], wmax[3]));
}

extern "C" void kernel_launch(void* const* d_in, const int* in_sizes, int n_in,
                              void* d_out, int out_size, void* d_ws, size_t ws_size,
                              hipStream_t stream) {
  const float* embed = (const float*)d_in[0];   // [256,128,768]
  const float* label = (const float*)d_in[1];   // [200,8,768]
  float* out = (float*)d_out;                   // [128,200]

  const size_t szA = (size_t)32768 * 768 * 2;        // 50,331,648
  const size_t szB = (size_t)1664 * 768 * 2;         //  2,555,904
  const size_t szS = (size_t)1664 * 2048 * 4;        // 13,631,488

  if (ws_size < szA + szB + szS) {
    dim3 g(128, 200);
    fallback_kernel<<<g, 256, 0, stream>>>(embed, label, out);
    return;
  }

  unsigned short* Ap = (unsigned short*)d_ws;
  unsigned short* Bp = (unsigned short*)((char*)d_ws + szA);
  float* scratch     = (float*)((char*)d_ws + szA + szB);

  normalize_all<<<8608, 256, 0, stream>>>(embed, label, Ap, Bp);
  gemm_store_kernel<<<1664, 512, 0, stream>>>(Ap, Bp, scratch);
  reduce_kernel<<<104, 256, 0, stream>>>(scratch, out);
}